// Round 2
// baseline (3578.017 us; speedup 1.0000x reference)
//
#include <hip/hip_runtime.h>
#include <cstdint>
#include <cstddef>

// SNN pipeline, round 11:
//  k1: unchanged from round 10 (fp32 k-ascending FMA chains, 8x16 reg tile,
//      conflict-free LDS maps, global prefetch; ~roofline for 157 TF fp32).
//  k2: RESTRUCTURED for MFMA-pipe occupancy. Round-10 analysis: MFMA pipe floor
//      = 1325 us (167.8M mfma_16x16x32 @ 2075 TF), measured 2400 us = 55% ==
//      MfmaUtil counter; idle 45% = 8-wave barrier lockstep w/ only 5 tt of
//      B-fragment reuse. Now: 4 waves x 256 thr, each wave owns ALL 10 timesteps
//      (acc[10][2][2] ~160 AGPR, 2 waves/SIMD via __launch_bounds__(256,2) ->
//      waves of 2 DIFFERENT blocks share a SIMD = decoupled barriers), 2x MFMA
//      per B read, no thalf m2-handoff. Staging via global_load_lds width=16
//      (fragment-linear slot map IS base+lane*16, wave-uniform base), 2-phase
//      schedule: STAGE(buf^1) at top (readers of buf^1 passed previous
//      end-of-iter barrier -> race-free), compute buf, vmcnt(0)+raw barrier
//      (loads flew under the MFMA phase -> drain is free).
//      Numerics BIT-IDENTICAL to round 9/10: same per-element MFMA sequence,
//      same fragments, same LIF-2 chain order, same po layout.
//  k3: unchanged.
// ws: w2d 4MiB @0 | s1bits 128MiB @16MiB | po 80MiB @160MiB

typedef _Float16 f16;
typedef _Float16 f16x8 __attribute__((ext_vector_type(8)));
typedef float f32x4 __attribute__((ext_vector_type(4)));
typedef int i32x4 __attribute__((ext_vector_type(4)));
typedef unsigned int u32;

#define MFMA16(A, B, C) __builtin_amdgcn_mfma_f32_16x16x32_f16(A, B, C, 0, 0, 0)

static constexpr int BSZ = 65536;
static constexpr int IN = 512;
static constexpr int H = 1024;

__device__ __forceinline__ void gl_lds16(const void* g, void* l) {
    __builtin_amdgcn_global_load_lds(
        (const __attribute__((address_space(1))) u32*)g,
        (__attribute__((address_space(3))) u32*)l, 16, 0, 0);
}

// W2[k][j] fp32 -> w2d[plane][j][k] f16 Dekker limbs: plane0 = f16(w),
// plane1 = f16((w - hi) * 2^11).
__global__ void prep_dekker(const float* __restrict__ src, f16* __restrict__ dst) {
    int idx = blockIdx.x * 256 + threadIdx.x;
    int k = idx >> 10;
    int j = idx & 1023;
    float w = src[(size_t)k * 1024 + j];
    f16 hi = (f16)w;
    float lo = (w - (float)hi) * 2048.0f;
    size_t o = (size_t)j * 1024 + k;
    dst[o] = hi;
    dst[o + (size_t)H * H] = (f16)lo;
}

// k1: fp32 k-ordered FMA-chain GEMM (BLAS-replica) + fp32-replica LIF -> masks.
// tile 128 b-rows x 256 h-cols, 256 threads = 16 ht x 16 bt, thread = 8b x 16h.
__global__ __launch_bounds__(256, 2) void k1_chain(
    const float* __restrict__ x, const float* __restrict__ w1,
    const float* __restrict__ b1, unsigned short* __restrict__ s1b) {
    __shared__ float xs[32][132];   // [k][b]; stride 132: rows 16B-aligned, banks spread
    __shared__ float ws[32][256];   // [k][h]
    const int hblk = blockIdx.x;    // 4
    const int bblk = blockIdx.y;    // 512
    const int tid = threadIdx.x;
    const int ht = tid & 15, bt = tid >> 4;
    const int h0 = hblk * 256, b0 = bblk * 128;

    float acc[8][16] = {};

    float4 xv[4], wv[8];
#pragma unroll
    for (int i = 0; i < 4; ++i) {
        int idx = tid + 256 * i;            // 1024 f4: 128 rows x 8 segs
        int br = idx >> 3, ks = idx & 7;
        xv[i] = *(const float4*)&x[(size_t)(b0 + br) * IN + ks * 4];
    }
#pragma unroll
    for (int i = 0; i < 8; ++i) {
        int idx = tid + 256 * i;            // 2048 f4: 32 rows x 64 segs
        int kr = idx >> 6, c4 = idx & 63;
        wv[i] = *(const float4*)&w1[(size_t)kr * H + h0 + c4 * 4];
    }

    for (int kc = 0; kc < 512; kc += 32) {
        __syncthreads();                    // prev compute's LDS reads done
#pragma unroll
        for (int i = 0; i < 4; ++i) {
            int idx = tid + 256 * i;
            int br = idx >> 3, ks = idx & 7;
            xs[ks * 4 + 0][br] = xv[i].x;
            xs[ks * 4 + 1][br] = xv[i].y;
            xs[ks * 4 + 2][br] = xv[i].z;
            xs[ks * 4 + 3][br] = xv[i].w;
        }
#pragma unroll
        for (int i = 0; i < 8; ++i) {
            int idx = tid + 256 * i;
            int kr = idx >> 6, c4 = idx & 63;
            *(float4*)&ws[kr][c4 * 4] = wv[i];
        }
        __syncthreads();
        int kn = (kc + 32) & 511;           // wraps to 0 on last chunk (dummy)
#pragma unroll
        for (int i = 0; i < 4; ++i) {
            int idx = tid + 256 * i;
            int br = idx >> 3, ks = idx & 7;
            xv[i] = *(const float4*)&x[(size_t)(b0 + br) * IN + kn + ks * 4];
        }
#pragma unroll
        for (int i = 0; i < 8; ++i) {
            int idx = tid + 256 * i;
            int kr = idx >> 6, c4 = idx & 63;
            wv[i] = *(const float4*)&w1[(size_t)(kn + kr) * H + h0 + c4 * 4];
        }
#pragma unroll 2
        for (int k = 0; k < 32; ++k) {
            float xr[8];
            *(float4*)&xr[0] = *(const float4*)&xs[k][bt * 8];
            *(float4*)&xr[4] = *(const float4*)&xs[k][bt * 8 + 4];
            float wr[16];
#pragma unroll
            for (int g = 0; g < 4; ++g)
                *(float4*)&wr[g * 4] = *(const float4*)&ws[k][ht * 4 + 64 * g];
#pragma unroll
            for (int i = 0; i < 8; ++i)
#pragma unroll
                for (int j = 0; j < 16; ++j)
                    acc[i][j] = fmaf(xr[i], wr[j], acc[i][j]);  // strict k-order chain
        }
    }

    float b1v[16];
#pragma unroll
    for (int g = 0; g < 4; ++g)
#pragma unroll
        for (int m = 0; m < 4; ++m)
            b1v[g * 4 + m] = b1[h0 + g * 64 + ht * 4 + m];
#pragma unroll
    for (int i = 0; i < 8; ++i) {
        unsigned short outb[16];
#pragma unroll
        for (int j = 0; j < 16; ++j) {
            float c = __fadd_rn(acc[i][j], b1v[j]);
            float m = 0.0f;
            unsigned bits = 0u;
#pragma unroll
            for (int t = 0; t < 10; ++t) {
                float rst = (m > 1.0f) ? 1.0f : 0.0f;
                m = __fmul_rn(0.9f, m);
                m = __fadd_rn(m, c);
                m = __fsub_rn(m, rst);
                if (m > 1.0f) bits |= (1u << t);
            }
            outb[j] = (unsigned short)bits;
        }
        size_t row = (size_t)(b0 + bt * 8 + i);
#pragma unroll
        for (int g = 0; g < 4; ++g)
            *(int2*)&s1b[row * H + h0 + g * 64 + ht * 4] = ((const int2*)outb)[g];
    }
}

// k2: spike GEMM. Block = 64 rows x 32 cols, 256 threads = 4 waves; each wave
// owns one 16-row strip x 32 cols x ALL 10 timesteps. Fragment-linear LDS,
// BK=64, global_load_lds staging, 2-phase schedule.
__global__ __launch_bounds__(256, 2) void k2_spikes_gemm(
    const unsigned short* __restrict__ s1bits, const f16* __restrict__ w2d,
    const float* __restrict__ b2, const float* __restrict__ wo,
    float* __restrict__ po) {
    __shared__ i32x4 AL[2][2][4][64];       // [buf][kch][strip][lane-slot] 16 KB
    __shared__ i32x4 BL[2][2][2][2][64];    // [buf][kch][plane][cf][lane-slot] 16 KB
    const int jblk = blockIdx.x, bblk = blockIdx.y;
    const int tid = threadIdx.x;
    const int lane = tid & 63, wave = tid >> 6;
    const int l15 = lane & 15, loct = lane >> 4;
    const int bpW = wave >> 1, bcfW = wave & 1;   // B staging role of this wave

    // per-lane global sources; LDS dest = wave-uniform base + lane*16
    // (slot = (seg<<4)|row15 == lane), exactly global_load_lds semantics.
    const unsigned short* gA =
        s1bits + (size_t)(bblk * 64 + wave * 16 + l15) * 1024 + loct * 8;
    const f16* gB = w2d + (size_t)bpW * H * H
                  + (size_t)(jblk * 32 + bcfW * 16 + l15) * 1024 + loct * 8;

    f32x4 acc[10][2][2] = {};   // [tt][plane][colfrag] -> AGPR file

    // prologue: stage buf0 (kc=0)
    gl_lds16(gA,      &AL[0][0][wave][0]);
    gl_lds16(gA + 32, &AL[0][1][wave][0]);
    gl_lds16(gB,      &BL[0][0][bpW][bcfW][0]);
    gl_lds16(gB + 32, &BL[0][1][bpW][bcfW][0]);
    asm volatile("s_waitcnt vmcnt(0)" ::: "memory");
    __builtin_amdgcn_s_barrier();

    typedef union { i32x4 i; unsigned long long u[2]; f16x8 h; } U;

    int buf = 0;
    for (int kc = 0; kc < 1024; kc += 64) {
        const int kn = (kc + 64) & 1023;    // wraps to 0 on last iter (dummy)
        // stage next K-tile into buf^1: its readers passed the PREVIOUS
        // end-of-iter barrier, so the async writes are race-free.
        gl_lds16(gA + kn,      &AL[buf ^ 1][0][wave][0]);
        gl_lds16(gA + kn + 32, &AL[buf ^ 1][1][wave][0]);
        gl_lds16(gB + kn,      &BL[buf ^ 1][0][bpW][bcfW][0]);
        gl_lds16(gB + kn + 32, &BL[buf ^ 1][1][bpW][bcfW][0]);
#pragma unroll
        for (int kch = 0; kch < 2; ++kch) {
            U m;
            m.i = AL[buf][kch][wave][lane];
            f16x8 bf[2][2];
#pragma unroll
            for (int p = 0; p < 2; ++p)
#pragma unroll
                for (int cf = 0; cf < 2; ++cf) {
                    U b; b.i = BL[buf][kch][p][cf][lane];
                    bf[p][cf] = b.h;
                }
#pragma unroll
            for (int tt = 0; tt < 10; ++tt) {
                const int sh = 10 - tt;
                U r;
                r.u[0] = (m.u[0] << sh) & 0x0400040004000400ULL;
                r.u[1] = (m.u[1] << sh) & 0x0400040004000400ULL;
                acc[tt][0][0] = MFMA16(r.h, bf[0][0], acc[tt][0][0]);
                acc[tt][0][1] = MFMA16(r.h, bf[0][1], acc[tt][0][1]);
                acc[tt][1][0] = MFMA16(r.h, bf[1][0], acc[tt][1][0]);
                acc[tt][1][1] = MFMA16(r.h, bf[1][1], acc[tt][1][1]);
            }
        }
        // stage loads flew under ~1550 cyc of MFMA -> drain is ~free
        asm volatile("s_waitcnt vmcnt(0)" ::: "memory");
        __builtin_amdgcn_s_barrier();
        buf ^= 1;
    }

    // epilogue: Dekker combine (unpack scale folded in: 16384, 8),
    // fp32-replica LIF-2, all 10 timesteps in this wave (no handoff).
    int col0 = jblk * 32 + l15;
    float b2v0 = b2[col0], b2v1 = b2[col0 + 16];
    double wov0 = (double)wo[col0], wov1 = (double)wo[col0 + 16];
    int rowb = bblk * 64 + wave * 16 + loct * 4;
    float m2a[4] = {0.0f, 0.0f, 0.0f, 0.0f};
    float m2b[4] = {0.0f, 0.0f, 0.0f, 0.0f};

#pragma unroll
    for (int tt = 0; tt < 10; ++tt) {
#pragma unroll
        for (int r = 0; r < 4; ++r) {
            float i0 = (float)((double)acc[tt][0][0][r] * 16384.0 + (double)acc[tt][1][0][r] * 8.0);
            i0 = __fadd_rn(i0, b2v0);
            float rst0 = (m2a[r] > 1.0f) ? 1.0f : 0.0f;
            m2a[r] = __fmul_rn(0.9f, m2a[r]);
            m2a[r] = __fadd_rn(m2a[r], i0);
            m2a[r] = __fsub_rn(m2a[r], rst0);
            float i1 = (float)((double)acc[tt][0][1][r] * 16384.0 + (double)acc[tt][1][1][r] * 8.0);
            i1 = __fadd_rn(i1, b2v1);
            float rst1 = (m2b[r] > 1.0f) ? 1.0f : 0.0f;
            m2b[r] = __fmul_rn(0.9f, m2b[r]);
            m2b[r] = __fadd_rn(m2b[r], i1);
            m2b[r] = __fsub_rn(m2b[r], rst1);
            double pv = ((m2a[r] > 1.0f) ? wov0 : 0.0) + ((m2b[r] > 1.0f) ? wov1 : 0.0);
            pv += __shfl_xor(pv, 1);
            pv += __shfl_xor(pv, 2);
            pv += __shfl_xor(pv, 4);
            pv += __shfl_xor(pv, 8);
            if (l15 == r)
                po[(size_t)(tt * 32 + jblk) * BSZ + rowb + r] = (float)pv;
        }
    }
}

// k3: sum 32 partials (ascending j-blocks), fp32-replica LIF-out, mean.
__global__ void k3_out(const float* __restrict__ po, const float* __restrict__ bo,
                       float* __restrict__ out) {
    int b = blockIdx.x * 256 + threadIdx.x;
    float mo = 0.0f, s = 0.0f;
    float bov = bo[0];
    for (int t = 0; t < 10; ++t) {
        float inp = 0.0f;
#pragma unroll
        for (int jb = 0; jb < 32; ++jb) inp += po[(size_t)(t * 32 + jb) * BSZ + b];
        inp = __fadd_rn(inp, bov);
        float rst = (mo > 1.0f) ? 1.0f : 0.0f;
        mo = __fmul_rn(0.9f, mo);
        mo = __fadd_rn(mo, inp);
        mo = __fsub_rn(mo, rst);
        s += mo;
    }
    out[b] = s / 10.0f;
}

extern "C" void kernel_launch(void* const* d_in, const int* in_sizes, int n_in,
                              void* d_out, int out_size, void* d_ws, size_t ws_size,
                              hipStream_t stream) {
    (void)in_sizes; (void)n_in; (void)out_size; (void)ws_size;
    const float* x  = (const float*)d_in[0];
    const float* W1 = (const float*)d_in[1];
    const float* b1 = (const float*)d_in[2];
    const float* W2 = (const float*)d_in[3];
    const float* b2 = (const float*)d_in[4];
    const float* Wo = (const float*)d_in[5];
    const float* bo = (const float*)d_in[6];
    float* out = (float*)d_out;

    char* ws = (char*)d_ws;
    f16* w2d = (f16*)ws;                                                   // 4 MiB @ 0
    unsigned short* s1bits = (unsigned short*)(ws + ((size_t)16 << 20));   // 128 MiB
    float* po = (float*)(ws + ((size_t)160 << 20));                        // 80 MiB

    prep_dekker<<<dim3((H * H) / 256), 256, 0, stream>>>(W2, w2d);
    k1_chain<<<dim3(4, BSZ / 128), 256, 0, stream>>>(x, W1, b1, s1bits);
    k2_spikes_gemm<<<dim3(H / 32, BSZ / 64), 256, 0, stream>>>(s1bits, w2d, b2, Wo, po);
    k3_out<<<dim3(BSZ / 256), 256, 0, stream>>>(po, bo, out);
}

// Round 3
// 3168.083 us; speedup vs baseline: 1.1294x; 1.1294x over previous
//
#include <hip/hip_runtime.h>
#include <cstdint>
#include <cstddef>

// SNN pipeline, round 12:
//  k1: unchanged from round 10 (fp32 k-ascending FMA chains, 8x16 reg tile,
//      conflict-free LDS maps, global prefetch).
//  k2: round-9 8-wave geometry (proven 57% MfmaUtil) + T3/T4/T5 schedule:
//      - global_load_lds width-16 staging (fragment-linear slot = base+lane*16),
//        waves 0-3 stage A strips, waves 4-7 stage B roles, 2 gloads/wave/tile.
//      - depth-3 LDS pipeline (3 bufs, 48 KB), counted s_waitcnt vmcnt(2) per
//        tile (never drain to 0 in-loop), one raw s_barrier per tile.
//      - ds_reads at tile top (kch1 reads fly under kch0's MFMA cluster),
//        s_setprio(1) around each 20-MFMA cluster.
//      - m2x handoff aliased onto buf0's A region (dead after K-loop; tail
//        dummy prefetches only target bufs 1/2).
//      Numerics BIT-IDENTICAL to round 9: same MFMA sequence/fragments, same
//      LIF-2 chains + thalf handoff, same po layout.
//  k3: unchanged.
// ws: w2d 4MiB @0 | s1bits 128MiB @16MiB | po 80MiB @160MiB

typedef _Float16 f16;
typedef _Float16 f16x8 __attribute__((ext_vector_type(8)));
typedef float f32x4 __attribute__((ext_vector_type(4)));
typedef int i32x4 __attribute__((ext_vector_type(4)));
typedef unsigned int u32;

#define MFMA16(A, B, C) __builtin_amdgcn_mfma_f32_16x16x32_f16(A, B, C, 0, 0, 0)

static constexpr int BSZ = 65536;
static constexpr int IN = 512;
static constexpr int H = 1024;

__device__ __forceinline__ void gl_lds16(const void* g, void* l) {
    __builtin_amdgcn_global_load_lds(
        (const __attribute__((address_space(1))) u32*)g,
        (__attribute__((address_space(3))) u32*)l, 16, 0, 0);
}

// W2[k][j] fp32 -> w2d[plane][j][k] f16 Dekker limbs: plane0 = f16(w),
// plane1 = f16((w - hi) * 2^11).
__global__ void prep_dekker(const float* __restrict__ src, f16* __restrict__ dst) {
    int idx = blockIdx.x * 256 + threadIdx.x;
    int k = idx >> 10;
    int j = idx & 1023;
    float w = src[(size_t)k * 1024 + j];
    f16 hi = (f16)w;
    float lo = (w - (float)hi) * 2048.0f;
    size_t o = (size_t)j * 1024 + k;
    dst[o] = hi;
    dst[o + (size_t)H * H] = (f16)lo;
}

// k1: fp32 k-ordered FMA-chain GEMM (BLAS-replica) + fp32-replica LIF -> masks.
// tile 128 b-rows x 256 h-cols, 256 threads = 16 ht x 16 bt, thread = 8b x 16h.
__global__ __launch_bounds__(256, 2) void k1_chain(
    const float* __restrict__ x, const float* __restrict__ w1,
    const float* __restrict__ b1, unsigned short* __restrict__ s1b) {
    __shared__ float xs[32][132];   // [k][b]; stride 132: rows 16B-aligned, banks spread
    __shared__ float ws[32][256];   // [k][h]
    const int hblk = blockIdx.x;    // 4
    const int bblk = blockIdx.y;    // 512
    const int tid = threadIdx.x;
    const int ht = tid & 15, bt = tid >> 4;
    const int h0 = hblk * 256, b0 = bblk * 128;

    float acc[8][16] = {};

    float4 xv[4], wv[8];
#pragma unroll
    for (int i = 0; i < 4; ++i) {
        int idx = tid + 256 * i;            // 1024 f4: 128 rows x 8 segs
        int br = idx >> 3, ks = idx & 7;
        xv[i] = *(const float4*)&x[(size_t)(b0 + br) * IN + ks * 4];
    }
#pragma unroll
    for (int i = 0; i < 8; ++i) {
        int idx = tid + 256 * i;            // 2048 f4: 32 rows x 64 segs
        int kr = idx >> 6, c4 = idx & 63;
        wv[i] = *(const float4*)&w1[(size_t)kr * H + h0 + c4 * 4];
    }

    for (int kc = 0; kc < 512; kc += 32) {
        __syncthreads();                    // prev compute's LDS reads done
#pragma unroll
        for (int i = 0; i < 4; ++i) {
            int idx = tid + 256 * i;
            int br = idx >> 3, ks = idx & 7;
            xs[ks * 4 + 0][br] = xv[i].x;
            xs[ks * 4 + 1][br] = xv[i].y;
            xs[ks * 4 + 2][br] = xv[i].z;
            xs[ks * 4 + 3][br] = xv[i].w;
        }
#pragma unroll
        for (int i = 0; i < 8; ++i) {
            int idx = tid + 256 * i;
            int kr = idx >> 6, c4 = idx & 63;
            *(float4*)&ws[kr][c4 * 4] = wv[i];
        }
        __syncthreads();
        int kn = (kc + 32) & 511;           // wraps to 0 on last chunk (dummy)
#pragma unroll
        for (int i = 0; i < 4; ++i) {
            int idx = tid + 256 * i;
            int br = idx >> 3, ks = idx & 7;
            xv[i] = *(const float4*)&x[(size_t)(b0 + br) * IN + kn + ks * 4];
        }
#pragma unroll
        for (int i = 0; i < 8; ++i) {
            int idx = tid + 256 * i;
            int kr = idx >> 6, c4 = idx & 63;
            wv[i] = *(const float4*)&w1[(size_t)(kn + kr) * H + h0 + c4 * 4];
        }
#pragma unroll 2
        for (int k = 0; k < 32; ++k) {
            float xr[8];
            *(float4*)&xr[0] = *(const float4*)&xs[k][bt * 8];
            *(float4*)&xr[4] = *(const float4*)&xs[k][bt * 8 + 4];
            float wr[16];
#pragma unroll
            for (int g = 0; g < 4; ++g)
                *(float4*)&wr[g * 4] = *(const float4*)&ws[k][ht * 4 + 64 * g];
#pragma unroll
            for (int i = 0; i < 8; ++i)
#pragma unroll
                for (int j = 0; j < 16; ++j)
                    acc[i][j] = fmaf(xr[i], wr[j], acc[i][j]);  // strict k-order chain
        }
    }

    float b1v[16];
#pragma unroll
    for (int g = 0; g < 4; ++g)
#pragma unroll
        for (int m = 0; m < 4; ++m)
            b1v[g * 4 + m] = b1[h0 + g * 64 + ht * 4 + m];
#pragma unroll
    for (int i = 0; i < 8; ++i) {
        unsigned short outb[16];
#pragma unroll
        for (int j = 0; j < 16; ++j) {
            float c = __fadd_rn(acc[i][j], b1v[j]);
            float m = 0.0f;
            unsigned bits = 0u;
#pragma unroll
            for (int t = 0; t < 10; ++t) {
                float rst = (m > 1.0f) ? 1.0f : 0.0f;
                m = __fmul_rn(0.9f, m);
                m = __fadd_rn(m, c);
                m = __fsub_rn(m, rst);
                if (m > 1.0f) bits |= (1u << t);
            }
            outb[j] = (unsigned short)bits;
        }
        size_t row = (size_t)(b0 + bt * 8 + i);
#pragma unroll
        for (int g = 0; g < 4; ++g)
            *(int2*)&s1b[row * H + h0 + g * 64 + ht * 4] = ((const int2*)outb)[g];
    }
}

// k2: spike GEMM. Block = 64 rows x 32 cols, 512 threads = 8 waves:
// wave = (strip = w&3) x (thalf = w>>2). Fragment-linear LDS, BK=64,
// depth-3 global_load_lds pipeline with counted vmcnt(2), setprio MFMA.
__global__ __launch_bounds__(512, 4) void k2_spikes_gemm(
    const unsigned short* __restrict__ s1bits, const f16* __restrict__ w2d,
    const float* __restrict__ b2, const float* __restrict__ wo,
    float* __restrict__ po) {
    // [3 bufs][kch][role][slot] fragment-linear; m2x aliases buf0's A region
    __shared__ __align__(16) char ldsraw[49152];
    i32x4 (*AL)[2][4][64]    = (i32x4 (*)[2][4][64])ldsraw;            // 3x8KB
    i32x4 (*BL)[2][2][2][64] = (i32x4 (*)[2][2][2][64])(ldsraw + 24576); // 3x8KB
    float (*m2x)[64][8]      = (float (*)[64][8])ldsraw;               // 8KB alias

    const int jblk = blockIdx.x, bblk = blockIdx.y;
    const int tid = threadIdx.x;
    const int lane = tid & 63, wave = tid >> 6;
    const int strip = wave & 3, thalf = wave >> 2;
    const int l15 = lane & 15, loct = lane >> 4;
    const int t0 = thalf * 5;

    // staging roles: waves 0-3 stage A strip w (2 gloads/tile: kch0, kch1);
    // waves 4-7 stage B (plane bp, colfrag bcf). slot index == lane, so the
    // LDS dest is wave-uniform base + lane*16 == global_load_lds semantics,
    // and the per-lane global source matches round 9's fragment placement.
    const bool stB = (wave >= 4);
    const int bp = (wave >> 1) & 1, bcf = wave & 1;
    const unsigned short* gA =
        s1bits + (size_t)(bblk * 64 + strip * 16 + l15) * 1024 + loct * 8;
    const f16* gB = w2d + (size_t)bp * H * H
                  + (size_t)(jblk * 32 + bcf * 16 + l15) * 1024 + loct * 8;

    f32x4 acc[5][2][2] = {};   // [tt][plane][colfrag] = 80 acc regs

    typedef union { i32x4 i; unsigned long long u[2]; f16x8 h; } U;

#define STAGE(t_)                                                        \
    do {                                                                 \
        int bi_ = (t_) % 3;                                              \
        int kk_ = ((t_) * 64) & 1023;                                    \
        if (stB) {                                                       \
            gl_lds16(gB + kk_,      &BL[bi_][0][bp][bcf][0]);            \
            gl_lds16(gB + kk_ + 32, &BL[bi_][1][bp][bcf][0]);            \
        } else {                                                         \
            gl_lds16(gA + kk_,      &AL[bi_][0][strip][0]);              \
            gl_lds16(gA + kk_ + 32, &AL[bi_][1][strip][0]);              \
        }                                                                \
    } while (0)

    // prologue: stage tiles 0 and 1; release tile 0
    STAGE(0);
    STAGE(1);
    asm volatile("s_waitcnt vmcnt(2)" ::: "memory");
    __builtin_amdgcn_s_barrier();

    for (int t = 0; t < 16; ++t) {
        const int bi = t % 3;
        STAGE(t + 2);   // wraps: dummy tail prefetches land in bufs 1/2 only
#pragma unroll
        for (int kch = 0; kch < 2; ++kch) {
            U m;
            m.i = AL[bi][kch][strip][lane];
            f16x8 bf[2][2];
#pragma unroll
            for (int p = 0; p < 2; ++p)
#pragma unroll
                for (int cf = 0; cf < 2; ++cf) {
                    U b; b.i = BL[bi][kch][p][cf][lane];
                    bf[p][cf] = b.h;
                }
            __builtin_amdgcn_s_setprio(1);
#pragma unroll
            for (int tt = 0; tt < 5; ++tt) {
                const int sh = 10 - (t0 + tt);
                U r;
                r.u[0] = (m.u[0] << sh) & 0x0400040004000400ULL;
                r.u[1] = (m.u[1] << sh) & 0x0400040004000400ULL;
                acc[tt][0][0] = MFMA16(r.h, bf[0][0], acc[tt][0][0]);
                acc[tt][0][1] = MFMA16(r.h, bf[0][1], acc[tt][0][1]);
                acc[tt][1][0] = MFMA16(r.h, bf[1][0], acc[tt][1][0]);
                acc[tt][1][1] = MFMA16(r.h, bf[1][1], acc[tt][1][1]);
            }
            __builtin_amdgcn_s_setprio(0);
        }
        // counted wait: outstanding = 2 (tile t+1) + 2 (tile t+2); waiting to
        // <=2 completes tile t+1's loads. Loads are never drained to 0.
        asm volatile("s_waitcnt vmcnt(2)" ::: "memory");
        __builtin_amdgcn_s_barrier();
    }
#undef STAGE

    // epilogue: Dekker combine (unpack scale folded in: 16384, 8),
    // fp32-replica LIF-2 split across t-halves with LDS m2 handoff.
    // m2x aliases buf0-A: last reads of buf0 (t=15) completed before the
    // final barrier; tail dummy gloads only write bufs 1/2.
    int col0 = jblk * 32 + l15;
    float b2v0 = b2[col0], b2v1 = b2[col0 + 16];
    double wov0 = (double)wo[col0], wov1 = (double)wo[col0 + 16];
    int rowb = bblk * 64 + strip * 16 + loct * 4;
    float m2a[4] = {0.0f, 0.0f, 0.0f, 0.0f};
    float m2b[4] = {0.0f, 0.0f, 0.0f, 0.0f};

    if (thalf == 0) {
#pragma unroll
        for (int tt = 0; tt < 5; ++tt) {
#pragma unroll
            for (int r = 0; r < 4; ++r) {
                float i0 = (float)((double)acc[tt][0][0][r] * 16384.0 + (double)acc[tt][1][0][r] * 8.0);
                i0 = __fadd_rn(i0, b2v0);
                float rst0 = (m2a[r] > 1.0f) ? 1.0f : 0.0f;
                m2a[r] = __fmul_rn(0.9f, m2a[r]);
                m2a[r] = __fadd_rn(m2a[r], i0);
                m2a[r] = __fsub_rn(m2a[r], rst0);
                float i1 = (float)((double)acc[tt][0][1][r] * 16384.0 + (double)acc[tt][1][1][r] * 8.0);
                i1 = __fadd_rn(i1, b2v1);
                float rst1 = (m2b[r] > 1.0f) ? 1.0f : 0.0f;
                m2b[r] = __fmul_rn(0.9f, m2b[r]);
                m2b[r] = __fadd_rn(m2b[r], i1);
                m2b[r] = __fsub_rn(m2b[r], rst1);
                double pv = ((m2a[r] > 1.0f) ? wov0 : 0.0) + ((m2b[r] > 1.0f) ? wov1 : 0.0);
                pv += __shfl_xor(pv, 1);
                pv += __shfl_xor(pv, 2);
                pv += __shfl_xor(pv, 4);
                pv += __shfl_xor(pv, 8);
                if (l15 == r)
                    po[(size_t)(tt * 32 + jblk) * BSZ + rowb + r] = (float)pv;
            }
        }
#pragma unroll
        for (int r = 0; r < 4; ++r) {
            m2x[strip][lane][r] = m2a[r];
            m2x[strip][lane][4 + r] = m2b[r];
        }
    }
    __syncthreads();
    if (thalf == 1) {
#pragma unroll
        for (int r = 0; r < 4; ++r) {
            m2a[r] = m2x[strip][lane][r];
            m2b[r] = m2x[strip][lane][4 + r];
        }
#pragma unroll
        for (int tt = 0; tt < 5; ++tt) {
#pragma unroll
            for (int r = 0; r < 4; ++r) {
                float i0 = (float)((double)acc[tt][0][0][r] * 16384.0 + (double)acc[tt][1][0][r] * 8.0);
                i0 = __fadd_rn(i0, b2v0);
                float rst0 = (m2a[r] > 1.0f) ? 1.0f : 0.0f;
                m2a[r] = __fmul_rn(0.9f, m2a[r]);
                m2a[r] = __fadd_rn(m2a[r], i0);
                m2a[r] = __fsub_rn(m2a[r], rst0);
                float i1 = (float)((double)acc[tt][0][1][r] * 16384.0 + (double)acc[tt][1][1][r] * 8.0);
                i1 = __fadd_rn(i1, b2v1);
                float rst1 = (m2b[r] > 1.0f) ? 1.0f : 0.0f;
                m2b[r] = __fmul_rn(0.9f, m2b[r]);
                m2b[r] = __fadd_rn(m2b[r], i1);
                m2b[r] = __fsub_rn(m2b[r], rst1);
                double pv = ((m2a[r] > 1.0f) ? wov0 : 0.0) + ((m2b[r] > 1.0f) ? wov1 : 0.0);
                pv += __shfl_xor(pv, 1);
                pv += __shfl_xor(pv, 2);
                pv += __shfl_xor(pv, 4);
                pv += __shfl_xor(pv, 8);
                if (l15 == r)
                    po[(size_t)((5 + tt) * 32 + jblk) * BSZ + rowb + r] = (float)pv;
            }
        }
    }
}

// k3: sum 32 partials (ascending j-blocks), fp32-replica LIF-out, mean.
__global__ void k3_out(const float* __restrict__ po, const float* __restrict__ bo,
                       float* __restrict__ out) {
    int b = blockIdx.x * 256 + threadIdx.x;
    float mo = 0.0f, s = 0.0f;
    float bov = bo[0];
    for (int t = 0; t < 10; ++t) {
        float inp = 0.0f;
#pragma unroll
        for (int jb = 0; jb < 32; ++jb) inp += po[(size_t)(t * 32 + jb) * BSZ + b];
        inp = __fadd_rn(inp, bov);
        float rst = (mo > 1.0f) ? 1.0f : 0.0f;
        mo = __fmul_rn(0.9f, mo);
        mo = __fadd_rn(mo, inp);
        mo = __fsub_rn(mo, rst);
        s += mo;
    }
    out[b] = s / 10.0f;
}

extern "C" void kernel_launch(void* const* d_in, const int* in_sizes, int n_in,
                              void* d_out, int out_size, void* d_ws, size_t ws_size,
                              hipStream_t stream) {
    (void)in_sizes; (void)n_in; (void)out_size; (void)ws_size;
    const float* x  = (const float*)d_in[0];
    const float* W1 = (const float*)d_in[1];
    const float* b1 = (const float*)d_in[2];
    const float* W2 = (const float*)d_in[3];
    const float* b2 = (const float*)d_in[4];
    const float* Wo = (const float*)d_in[5];
    const float* bo = (const float*)d_in[6];
    float* out = (float*)d_out;

    char* ws = (char*)d_ws;
    f16* w2d = (f16*)ws;                                                   // 4 MiB @ 0
    unsigned short* s1bits = (unsigned short*)(ws + ((size_t)16 << 20));   // 128 MiB
    float* po = (float*)(ws + ((size_t)160 << 20));                        // 80 MiB

    prep_dekker<<<dim3((H * H) / 256), 256, 0, stream>>>(W2, w2d);
    k1_chain<<<dim3(4, BSZ / 128), 256, 0, stream>>>(x, W1, b1, s1bits);
    k2_spikes_gemm<<<dim3(H / 32, BSZ / 64), 512, 0, stream>>>(s1bits, w2d, b2, Wo, po);
    k3_out<<<dim3(BSZ / 256), 256, 0, stream>>>(po, bo, out);
}